// Round 1
// baseline (620.532 us; speedup 1.0000x reference)
//
#include <hip/hip_runtime.h>
#include <cmath>

typedef float f4_t __attribute__((ext_vector_type(4)));

#define B_TOTAL   65536
#define FTW_SCALE 1024.0f
#define INV_SCALE (1.0f/1024.0f)

// ---------------------------------------------------------------------------
// Kernel 0: pack ft_w [1024][768] fp32 -> fp8(e4m3, x1024) into d_ws in
// fragment-sequential order: for tile (nc,kk) of shape [128 n][32 k],
//   ws[(nc*24+kk)*4096 + cfg*512 + lane*8 + j] = fp8(ft_w[nc*128+cfg*16+(lane&15)][kk*32+(lane>>4)*8+j])
// so the GEMM's b-frag load is simply  base + lane*8  (coalesced, conflict-free).
// ---------------------------------------------------------------------------
__global__ void pack_ftw_kernel(const float* __restrict__ ftw, char* __restrict__ ws)
{
    int t   = blockIdx.x * 256 + threadIdx.x;   // 0 .. 98303 (one 8-byte frag each)
    int nl  = t & 15;
    int q   = (t >> 4) & 3;
    int cfg = (t >> 6) & 7;
    int tk  = t >> 9;          // 0..191
    int kk  = tk % 24;
    int nc  = tk / 24;
    int row = nc * 128 + cfg * 16 + nl;     // 0..1023
    int k0  = kk * 32 + q * 8;              // 0..760
    const float* src = ftw + (size_t)row * 768 + k0;
    float4 x = *(const float4*)(src);
    float4 y = *(const float4*)(src + 4);
    int v0 = __builtin_amdgcn_cvt_pk_fp8_f32(x.x * FTW_SCALE, x.y * FTW_SCALE, 0, false);
    v0     = __builtin_amdgcn_cvt_pk_fp8_f32(x.z * FTW_SCALE, x.w * FTW_SCALE, v0, true);
    int v1 = __builtin_amdgcn_cvt_pk_fp8_f32(y.x * FTW_SCALE, y.y * FTW_SCALE, 0, false);
    v1     = __builtin_amdgcn_cvt_pk_fp8_f32(y.z * FTW_SCALE, y.w * FTW_SCALE, v1, true);
    int2 o; o.x = v0; o.y = v1;
    *(int2*)(ws + (size_t)t * 8) = o;       // coalesced
}

// ---------------------------------------------------------------------------
// Main fused kernel: 1 block = 32 samples. Computes w,b feature transforms
// (fp8 MFMA 16x16x32), blends with stm, clips, reduces 2048->8 (l1) in the
// epilogue, then l2/l3/sigmoid in a 32-thread tail. No barriers in K-loop.
// Waves: wm = sample half (16 samples), wn = column half (64 cols of 128-chunk).
// ---------------------------------------------------------------------------
__global__ __launch_bounds__(256, 3) void nnue_fused_kernel(
    const float* __restrict__ wf,  const float* __restrict__ bfeat,
    const float* __restrict__ stm, const char*  __restrict__ ftw8,
    const float* __restrict__ ftb, const float* __restrict__ l1w,
    const float* __restrict__ l1b, const float* __restrict__ l2w,
    const float* __restrict__ l2b, const float* __restrict__ l3w,
    const float* __restrict__ l3b, float* __restrict__ out)
{
    __shared__ char  Atile[64 * 784];        // 64 rows (32 white + 32 black) x 768 fp8, +16B pad
    __shared__ float l1acc[2][32][8];        // [wn][sample][o]

    const int t    = threadIdx.x;
    const int lane = t & 63;
    const int wave = t >> 6;
    const int wm   = wave >> 1;              // 0..1
    const int wn   = wave & 1;               // 0..1
    const int q    = lane >> 4;              // 0..3
    const int nl   = lane & 15;
    const int s0   = blockIdx.x * 32;

    // ---- stage A: white rows 0..31, black rows 32..63, fp32 -> fp8 ----
    {
        const int row = t >> 3;              // 0..31
        const int c8  = t & 7;
        const float4* wsrc = (const float4*)(wf    + (size_t)(s0 + row) * 768);
        const float4* bsrc = (const float4*)(bfeat + (size_t)(s0 + row) * 768);
        char* dw = &Atile[row * 784];
        char* db = &Atile[(row + 32) * 784];
        #pragma unroll
        for (int it = 0; it < 24; ++it) {
            int f4i = c8 + it * 8;           // 0..191
            float4 x = wsrc[f4i];
            int v = __builtin_amdgcn_cvt_pk_fp8_f32(x.x, x.y, 0, false);
            v     = __builtin_amdgcn_cvt_pk_fp8_f32(x.z, x.w, v, true);
            *(int*)(dw + f4i * 4) = v;
            float4 y = bsrc[f4i];
            int u = __builtin_amdgcn_cvt_pk_fp8_f32(y.x, y.y, 0, false);
            u     = __builtin_amdgcn_cvt_pk_fp8_f32(y.z, y.w, u, true);
            *(int*)(db + f4i * 4) = u;
        }
    }

    // stm for this lane's 4 sample rows (C/D layout: row = q*4+r)
    float sreg[4];
    #pragma unroll
    for (int r = 0; r < 4; ++r) sreg[r] = stm[s0 + wm * 16 + q * 4 + r];

    __syncthreads();

    float p[4][8];                           // l1 partials: [r][o]
    #pragma unroll
    for (int r = 0; r < 4; ++r)
        #pragma unroll
        for (int o = 0; o < 8; ++o) p[r][o] = 0.f;

    const char* bbase = ftw8 + wn * 2048 + (size_t)lane * 8;     // wn*4 frag groups
    const char* arW   = &Atile[(wm * 16 + nl) * 784 + q * 8];
    const char* arB   = arW + 32 * 784;

    for (int nc = 0; nc < 8; ++nc) {
        f4_t aw[4], ab[4];
        #pragma unroll
        for (int cf = 0; cf < 4; ++cf) {
            aw[cf] = (f4_t){0.f, 0.f, 0.f, 0.f};
            ab[cf] = (f4_t){0.f, 0.f, 0.f, 0.f};
        }
        const char* bnc = bbase + (size_t)nc * 24 * 4096;

        #pragma unroll 2
        for (int kk = 0; kk < 24; ++kk) {
            long a0 = *(const long*)(arW + kk * 32);
            long a1 = *(const long*)(arB + kk * 32);
            const char* bt = bnc + kk * 4096;
            long b0 = *(const long*)(bt);
            long b1 = *(const long*)(bt + 512);
            long b2 = *(const long*)(bt + 1024);
            long b3 = *(const long*)(bt + 1536);
            aw[0] = __builtin_amdgcn_mfma_f32_16x16x32_fp8_fp8(a0, b0, aw[0], 0, 0, 0);
            ab[0] = __builtin_amdgcn_mfma_f32_16x16x32_fp8_fp8(a1, b0, ab[0], 0, 0, 0);
            aw[1] = __builtin_amdgcn_mfma_f32_16x16x32_fp8_fp8(a0, b1, aw[1], 0, 0, 0);
            ab[1] = __builtin_amdgcn_mfma_f32_16x16x32_fp8_fp8(a1, b1, ab[1], 0, 0, 0);
            aw[2] = __builtin_amdgcn_mfma_f32_16x16x32_fp8_fp8(a0, b2, aw[2], 0, 0, 0);
            ab[2] = __builtin_amdgcn_mfma_f32_16x16x32_fp8_fp8(a1, b2, ab[2], 0, 0, 0);
            aw[3] = __builtin_amdgcn_mfma_f32_16x16x32_fp8_fp8(a0, b3, aw[3], 0, 0, 0);
            ab[3] = __builtin_amdgcn_mfma_f32_16x16x32_fp8_fp8(a1, b3, ab[3], 0, 0, 0);
        }

        // epilogue: blend + clip + l1 partial reduction over this 128-col chunk
        #pragma unroll
        for (int cf = 0; cf < 4; ++cf) {
            int j = nc * 128 + wn * 64 + cf * 16 + nl;   // global ft column
            float bias = ftb[j];
            float lo[8], hi[8];
            #pragma unroll
            for (int o = 0; o < 8; ++o) {
                lo[o] = l1w[o * 2048 + j];
                hi[o] = l1w[o * 2048 + 1024 + j];
            }
            #pragma unroll
            for (int r = 0; r < 4; ++r) {
                float wv = fmaf(aw[cf][r], INV_SCALE, bias);
                float bv = fmaf(ab[cf][r], INV_SCALE, bias);
                float d  = wv - bv;
                float first  = fmaf(sreg[r], d, bv);     // stm*w + (1-stm)*b
                float second = fmaf(-sreg[r], d, wv);    // stm*b + (1-stm)*w
                first  = fminf(fmaxf(first,  0.f), 1.f);
                second = fminf(fmaxf(second, 0.f), 1.f);
                #pragma unroll
                for (int o = 0; o < 8; ++o)
                    p[r][o] = fmaf(first, lo[o], fmaf(second, hi[o], p[r][o]));
            }
        }
    }

    // reduce partials across the 16 column-lanes (low 4 bits of lane)
    #pragma unroll
    for (int m = 1; m < 16; m <<= 1)
        #pragma unroll
        for (int r = 0; r < 4; ++r)
            #pragma unroll
            for (int o = 0; o < 8; ++o)
                p[r][o] += __shfl_xor(p[r][o], m);

    if (nl == 0) {
        #pragma unroll
        for (int r = 0; r < 4; ++r)
            #pragma unroll
            for (int o = 0; o < 8; ++o)
                l1acc[wn][wm * 16 + q * 4 + r][o] = p[r][o];
    }
    __syncthreads();

    // tail MLP: l1 bias+clip -> l2 -> l3 -> sigmoid
    if (t < 32) {
        float v[8];
        #pragma unroll
        for (int o = 0; o < 8; ++o)
            v[o] = fminf(fmaxf(l1acc[0][t][o] + l1acc[1][t][o] + l1b[o], 0.f), 1.f);
        float raw = l3b[0];
        #pragma unroll
        for (int u = 0; u < 32; ++u) {
            float h = l2b[u];
            #pragma unroll
            for (int o = 0; o < 8; ++o) h = fmaf(v[o], l2w[u * 8 + o], h);
            h = fminf(fmaxf(h, 0.f), 1.f);
            raw = fmaf(h, l3w[u], raw);
        }
        out[s0 + t]           = 1.0f / (1.0f + expf(-raw));
        out[B_TOTAL + s0 + t] = raw;
    }
}

extern "C" void kernel_launch(void* const* d_in, const int* in_sizes, int n_in,
                              void* d_out, int out_size, void* d_ws, size_t ws_size,
                              hipStream_t stream)
{
    const float* wf  = (const float*)d_in[0];
    const float* bf  = (const float*)d_in[1];
    const float* stm = (const float*)d_in[2];
    const float* ftw = (const float*)d_in[3];
    const float* ftb = (const float*)d_in[4];
    const float* l1w = (const float*)d_in[5];
    const float* l1b = (const float*)d_in[6];
    const float* l2w = (const float*)d_in[7];
    const float* l2b = (const float*)d_in[8];
    const float* l3w = (const float*)d_in[9];
    const float* l3b = (const float*)d_in[10];
    char* ws8 = (char*)d_ws;   // needs 768 KB for packed fp8 ft_w

    hipLaunchKernelGGL(pack_ftw_kernel, dim3(384), dim3(256), 0, stream, ftw, ws8);
    hipLaunchKernelGGL(nnue_fused_kernel, dim3(2048), dim3(256), 0, stream,
                       wf, bf, stm, ws8, ftb, l1w, l1b, l2w, l2b, l3w, l3b,
                       (float*)d_out);
}